// Round 6
// baseline (92.419 us; speedup 1.0000x reference)
//
#include <hip/hip_runtime.h>
#include <math.h>

#define OUT_H 7
#define OUT_W 7
#define N_C 256
#define N_IMG 2
#define FH 38
#define FW 38
#define HW (FH * FW)           // 1444 spatial positions
#define NUM_ROIS 256
#define SPATIAL_SCALE 0.0625f
#define SPITCH 257             // LDS floats per ij row (256 data + 1 pad)

// ---------------------------------------------------------------------------
// K1: NCHW -> NHWC transpose of feat into d_ws. featT[b][p][c], c contiguous.
// ---------------------------------------------------------------------------
__global__ __launch_bounds__(256) void transpose_nchw_nhwc(
    const float* __restrict__ feat, float* __restrict__ featT)
{
    __shared__ float tile[64][65];
    const int bid = blockIdx.x;            // N_IMG * 23 * 4 = 184
    const int b   = bid / (23 * 4);
    const int rem = bid % (23 * 4);
    const int p0  = (rem / 4) * 64;
    const int c0  = (rem % 4) * 64;
    const int tx  = threadIdx.x & 63;
    const int tz  = threadIdx.x >> 6;

    const int p = p0 + tx;
    if (p < HW) {
        #pragma unroll
        for (int s = 0; s < 64; s += 4)
            tile[tz + s][tx] = feat[((size_t)(b * N_C + c0 + tz + s)) * HW + p];
    }
    __syncthreads();
    #pragma unroll
    for (int s = 0; s < 64; s += 4) {
        const int pp = p0 + tz + s;
        if (pp < HW)
            featT[((size_t)(b * HW + pp)) * N_C + c0 + tx] = tile[tx][tz + s];
    }
}

// ---------------------------------------------------------------------------
// K2: fused pool + output transpose. One block per ROI (512 thr = 8 waves).
// Wave wv handles ij = wv, wv+8, ... (~6 windows; loads across windows are
// independent -> deep pipeline). Lane owns channels 4L..4L+3 (float4 from
// NHWC featT): window bounds wave-uniform, every load 1 KB coalesced, L2-
// resident. Results go to LDS [ij][comp][64] (lane-stride-1 writes and
// addr-stride-257 epilogue reads: both bank-conflict-free), then ONE
// coalesced sweep writes out[r][c][ij]. Kills the outT round-trip + K3.
// ---------------------------------------------------------------------------
__global__ __launch_bounds__(512) void roi_pool_fused(
    const float* __restrict__ featT,
    const float* __restrict__ rois,
    float* __restrict__ out)
{
    __shared__ float s_out[49 * SPITCH];   // 50372 B

    const int r    = blockIdx.x;
    const int lane = threadIdx.x & 63;
    const int wv   = threadIdx.x >> 6;     // 0..7

    const float* roi = rois + (size_t)r * 5;
    const int b  = (int)roi[0];
    const int x1 = (int)(roi[1] * SPATIAL_SCALE);  // floor (inputs >= 0)
    const int y1 = (int)(roi[2] * SPATIAL_SCALE);
    const int x2 = (int)(roi[3] * SPATIAL_SCALE);
    const int y2 = (int)(roi[4] * SPATIAL_SCALE);
    const int rh = y2 - y1 + 1;
    const int rw = x2 - x1 + 1;

    const float4* fb = (const float4*)featT + (size_t)b * HW * (N_C / 4) + lane;

    for (int ij = wv; ij < OUT_H * OUT_W; ij += 8) {
        const int i = ij / OUT_W;
        const int j = ij - i * OUT_W;
        const int hs = y1 + (i * rh) / OUT_H;               // Python floor-div
        const int he = y1 + ((i + 1) * rh + OUT_H - 1) / OUT_H;
        const int ws = x1 + (j * rw) / OUT_W;
        const int we = x1 + ((j + 1) * rw + OUT_W - 1) / OUT_W;

        float4 m0 = make_float4(-INFINITY, -INFINITY, -INFINITY, -INFINITY);
        float4 m1 = m0;
        for (int h = hs; h < he; ++h) {                     // wave-uniform
            const float4* rowp = fb + (size_t)(h * FW) * (N_C / 4);
            int w = ws;
            for (; w + 1 < we; w += 2) {
                const float4 v0 = rowp[(size_t)w * (N_C / 4)];
                const float4 v1 = rowp[(size_t)(w + 1) * (N_C / 4)];
                m0.x = fmaxf(m0.x, v0.x); m0.y = fmaxf(m0.y, v0.y);
                m0.z = fmaxf(m0.z, v0.z); m0.w = fmaxf(m0.w, v0.w);
                m1.x = fmaxf(m1.x, v1.x); m1.y = fmaxf(m1.y, v1.y);
                m1.z = fmaxf(m1.z, v1.z); m1.w = fmaxf(m1.w, v1.w);
            }
            if (w < we) {
                const float4 v0 = rowp[(size_t)w * (N_C / 4)];
                m0.x = fmaxf(m0.x, v0.x); m0.y = fmaxf(m0.y, v0.y);
                m0.z = fmaxf(m0.z, v0.z); m0.w = fmaxf(m0.w, v0.w);
            }
        }
        m0.x = fmaxf(m0.x, m1.x); m0.y = fmaxf(m0.y, m1.y);
        m0.z = fmaxf(m0.z, m1.z); m0.w = fmaxf(m0.w, m1.w);

        // [ij][comp][64]: lane-stride-1 -> conflict-free ds_write_b32 x4
        float* row = s_out + ij * SPITCH;
        row[0 * 64 + lane] = m0.x;
        row[1 * 64 + lane] = m0.y;
        row[2 * 64 + lane] = m0.z;
        row[3 * 64 + lane] = m0.w;
    }
    __syncthreads();

    // out[r][c][ij] <- s_out[ij][c&3][c>>2]; consecutive k -> consecutive
    // global addr (coalesced) and LDS addr stride 257 (bank stride 1).
    float* outr = out + (size_t)r * (N_C * 49);
    for (int k = threadIdx.x; k < N_C * 49; k += 512) {
        const int c  = k / 49;
        const int ij = k - c * 49;
        outr[k] = s_out[ij * SPITCH + (c & 3) * 64 + (c >> 2)];
    }
}

extern "C" void kernel_launch(void* const* d_in, const int* in_sizes, int n_in,
                              void* d_out, int out_size, void* d_ws, size_t ws_size,
                              hipStream_t stream) {
    const float* feat = (const float*)d_in[0];
    const float* rois = (const float*)d_in[1];
    float* out   = (float*)d_out;
    float* featT = (float*)d_ws;   // 2*1444*256*4 = 2.96 MB << ws_size

    transpose_nchw_nhwc<<<N_IMG * 23 * 4, 256, 0, stream>>>(feat, featT);
    roi_pool_fused<<<NUM_ROIS, 512, 0, stream>>>(featT, rois, out);
}